// Round 1
// baseline (651.393 us; speedup 1.0000x reference)
//
#include <hip/hip_runtime.h>

typedef __attribute__((ext_vector_type(8))) short bf16x8;   // 8 bf16 = 4 VGPRs
typedef __attribute__((ext_vector_type(4))) float f32x4;    // MFMA C/D

__device__ __forceinline__ float bf2f(unsigned short u){
    unsigned int v = ((unsigned int)u) << 16;
    return __builtin_bit_cast(float, v);
}
__device__ __forceinline__ unsigned short f2bf(float f){
    unsigned int u = __builtin_bit_cast(unsigned int, f);
    u += 0x7FFFu + ((u >> 16) & 1u);   // RTNE (no NaN inputs here)
    return (unsigned short)(u >> 16);
}

// ---- prep: W (K x 256) fp32 -> Wt (256 x K) bf16 (transposed) ----
__global__ void prep_wt(const float* __restrict__ W, unsigned short* __restrict__ Wt, int K){
    int k = blockIdx.x;
    int j = threadIdx.x;
    Wt[(size_t)j * K + k] = f2bf(W[(size_t)k * 256 + j]);
}

// ---- prep: x (b,m,d) fp32 -> Xt[b][d][m] bf16 ----
__global__ void prep_x(const float* __restrict__ x, unsigned short* __restrict__ Xt){
    int b = blockIdx.x;
    int t = threadIdx.x;
    #pragma unroll
    for (int it = 0; it < 8; it++){
        int o = it * 256 + t;          // o = d*32 + m
        int d = o >> 5, m = o & 31;
        Xt[(size_t)b * 2048 + o] = f2bf(x[(size_t)b * 2048 + m * 64 + d]);
    }
}

__global__ void init_out(float* __restrict__ out, const float* __restrict__ fcb){
    int i = blockIdx.x * 256 + threadIdx.x;
    if (i < 1024) out[i] = fcb[0];
}

// ---- fused CIN stage: Y = relu(Wt^T * Z + bias); emit h-half + fc partial ----
// Z[k=(m,n), c=(bb,d)] = Xt[b][d][m] * Hin[b][d][n], built per 32-k chunk in LDS.
// Block: 2 batch elems (c = bb*64+d, 128 cols), 4 waves; wave w owns j in [64w, 64w+64).
template<int NN, int LOG2NN, int KTOT, int JX, bool HAS_HOUT>
__global__ __launch_bounds__(256, 2) void cin_stage(
    const unsigned short* __restrict__ Xt,
    const unsigned short* __restrict__ Hin,
    const unsigned short* __restrict__ Wt,
    const float* __restrict__ bias,
    const float* __restrict__ fcW,      // pre-offset for this layer
    unsigned short* __restrict__ Hout,  // [b][d][n] bf16, n in [0,128); null if !HAS_HOUT
    float* __restrict__ out)
{
    constexpr int KT = KTOT / 32;
    __shared__ unsigned short smem[128 * 136];      // 34816 B
    unsigned short* Zl = smem;                      // [c:128][k:32 pad 40] during K-loop
    unsigned short* Yl = smem;                      // [n:128][c:128 pad 136] in epilogue

    const int t    = threadIdx.x;
    const int lane = t & 63;
    const int w    = t >> 6;
    const int li   = lane & 15;
    const int lq   = lane >> 4;
    const int bpair = blockIdx.x;

    f32x4 acc[4][8];
    #pragma unroll
    for (int jt = 0; jt < 4; jt++)
        #pragma unroll
        for (int ct = 0; ct < 8; ct++)
            acc[jt][ct] = (f32x4){0.f, 0.f, 0.f, 0.f};

    // Z-formation constants: this thread fills Zl[zc][zkh*16 .. +16)
    const int zc  = t & 127;
    const int zkh = t >> 7;
    const int zb  = bpair * 2 + (zc >> 6);
    const int zd  = zc & 63;
    const unsigned short* xrow = Xt + ((size_t)zb << 11) + (zd << 5);
    const unsigned short* hrow = Hin + ((size_t)((zb << 6) + zd) << LOG2NN);

    // A-fragment global base: lane reads Wt[j = w*64 + jt*16 + li][kt*32 + lq*8 .. +8)
    const unsigned short* wbase = Wt + (size_t)((w << 6) + li) * KTOT + (lq << 3);

    for (int kt = 0; kt < KT; kt++){
        __syncthreads();                 // previous iteration's B-reads done
        {   // build Z chunk
            int kg = (kt << 5) + (zkh << 4);
            int m  = kg >> LOG2NN;
            int n0 = kg & (NN - 1);
            float x0f = bf2f(xrow[m]);
            const uint4* hsrc = (const uint4*)(hrow + n0);
            uint4 h0 = hsrc[0], h1 = hsrc[1];
            uint4 zv[2];
            unsigned short* z = (unsigned short*)zv;
            const unsigned short* hu0 = (const unsigned short*)&h0;
            const unsigned short* hu1 = (const unsigned short*)&h1;
            #pragma unroll
            for (int q = 0; q < 8; q++) z[q]     = f2bf(x0f * bf2f(hu0[q]));
            #pragma unroll
            for (int q = 0; q < 8; q++) z[q + 8] = f2bf(x0f * bf2f(hu1[q]));
            uint4* zdst = (uint4*)(Zl + zc * 40 + (zkh << 4));
            zdst[0] = zv[0];
            zdst[1] = zv[1];
        }
        __syncthreads();
        // MFMA over the 32-k chunk
        bf16x8 A[4];
        const unsigned short* wk = wbase + (kt << 5);
        #pragma unroll
        for (int jt = 0; jt < 4; jt++)
            A[jt] = *(const bf16x8*)(wk + (size_t)jt * 16 * KTOT);
        #pragma unroll
        for (int ct = 0; ct < 8; ct++){
            bf16x8 B = *(const bf16x8*)(Zl + ((ct << 4) + li) * 40 + (lq << 3));
            #pragma unroll
            for (int jt = 0; jt < 4; jt++)
                acc[jt][ct] = __builtin_amdgcn_mfma_f32_16x16x32_bf16(A[jt], B, acc[jt][ct], 0, 0, 0);
        }
    }

    __syncthreads();     // all B-reads done before Yl overlays Zl

    // epilogue: bias + relu; fc partial sums; stage h-half into Yl
    float pfc0 = 0.f, pfc1 = 0.f;
    #pragma unroll
    for (int jt = 0; jt < 4; jt++){
        const int jb = (w << 6) + (jt << 4) + (lq << 2);
        float bv[4], fv[4];
        #pragma unroll
        for (int r = 0; r < 4; r++){
            int j = jb + r;
            bv[r] = bias[j];
            fv[r] = (j < JX) ? fcW[j] : 0.f;
        }
        #pragma unroll
        for (int ct = 0; ct < 8; ct++){
            f32x4 f = acc[jt][ct];
            int c = (ct << 4) + li;
            float ps = 0.f;
            #pragma unroll
            for (int r = 0; r < 4; r++){
                float y = f[r] + bv[r];
                y = y > 0.f ? y : 0.f;
                ps += fv[r] * y;
                if (HAS_HOUT){
                    int j = jb + r;
                    if (j >= 128)
                        Yl[(j - 128) * 136 + c] = f2bf(y);
                }
            }
            if (ct < 4) pfc0 += ps; else pfc1 += ps;
        }
    }
    #pragma unroll
    for (int off = 32; off; off >>= 1){
        pfc0 += __shfl_xor(pfc0, off, 64);
        pfc1 += __shfl_xor(pfc1, off, 64);
    }
    if (lane == 0){
        atomicAdd(out + bpair * 2 + 0, pfc0);
        atomicAdd(out + bpair * 2 + 1, pfc1);
    }

    if (HAS_HOUT){
        __syncthreads();
        // cooperative store: Hout[(bpair*128 + c)*128 + n] = Yl[n][c]
        const int c  = t >> 1;
        const int nh = (t & 1) << 6;
        unsigned short* gdst = Hout + (size_t)(bpair * 128 + c) * 128 + nh;
        #pragma unroll
        for (int i8 = 0; i8 < 8; i8++){
            uint4 tv;
            unsigned short* tmp = (unsigned short*)&tv;
            #pragma unroll
            for (int q = 0; q < 8; q++)
                tmp[q] = Yl[(nh + i8 * 8 + q) * 136 + c];
            *(uint4*)(gdst + i8 * 8) = tv;
        }
    }
}

extern "C" void kernel_launch(void* const* d_in, const int* in_sizes, int n_in,
                              void* d_out, int out_size, void* d_ws, size_t ws_size,
                              hipStream_t stream){
    const float* x   = (const float*)d_in[0];
    const float* W0  = (const float*)d_in[1];
    const float* b0  = (const float*)d_in[2];
    const float* W1  = (const float*)d_in[3];
    const float* b1  = (const float*)d_in[4];
    const float* W2  = (const float*)d_in[5];
    const float* b2  = (const float*)d_in[6];
    const float* fcW = (const float*)d_in[7];
    const float* fcb = (const float*)d_in[8];
    float* out = (float*)d_out;

    char* ws = (char*)d_ws;
    unsigned short* Xt  = (unsigned short*)(ws);             // 1024*64*32*2 = 4 MB
    unsigned short* Wt0 = (unsigned short*)(ws + 4194304);   // 256*1024*2  = 512 KB
    unsigned short* Wt1 = (unsigned short*)(ws + 4718592);   // 256*4096*2  = 2 MB
    unsigned short* Wt2 = (unsigned short*)(ws + 6815744);   // 2 MB
    unsigned short* H0  = (unsigned short*)(ws + 8912896);   // 1024*64*128*2 = 16 MB
    unsigned short* H1  = (unsigned short*)(ws + 25690112);  // 16 MB  (end 42467328)

    prep_wt<<<1024, 256, 0, stream>>>(W0, Wt0, 1024);
    prep_wt<<<4096, 256, 0, stream>>>(W1, Wt1, 4096);
    prep_wt<<<4096, 256, 0, stream>>>(W2, Wt2, 4096);
    prep_x <<<1024, 256, 0, stream>>>(x, Xt);
    init_out<<<4, 256, 0, stream>>>(out, fcb);

    cin_stage< 32, 5, 1024, 128, true ><<<512, 256, 0, stream>>>(Xt, Xt, Wt0, b0, fcW,       H0, out);
    cin_stage<128, 7, 4096, 128, true ><<<512, 256, 0, stream>>>(Xt, H0, Wt1, b1, fcW + 128, H1, out);
    cin_stage<128, 7, 4096, 256, false><<<512, 256, 0, stream>>>(Xt, H1, Wt2, b2, fcW + 256, nullptr, out);
}

// Round 2
// 399.937 us; speedup vs baseline: 1.6287x; 1.6287x over previous
//
#include <hip/hip_runtime.h>

typedef __attribute__((ext_vector_type(8))) short bf16x8;   // 8 bf16 = 4 VGPRs
typedef __attribute__((ext_vector_type(4))) float f32x4;    // MFMA C/D

__device__ __forceinline__ float bf2f(unsigned short u){
    unsigned int v = ((unsigned int)u) << 16;
    return __builtin_bit_cast(float, v);
}
__device__ __forceinline__ unsigned short f2bf(float f){
    unsigned int u = __builtin_bit_cast(unsigned int, f);
    u += 0x7FFFu + ((u >> 16) & 1u);   // RTNE (no NaN inputs here)
    return (unsigned short)(u >> 16);
}

// ---- prep: W (K x 256) fp32 -> Wt (256 x K) bf16 (transposed) ----
__global__ void prep_wt(const float* __restrict__ W, unsigned short* __restrict__ Wt, int K){
    int k = blockIdx.x;
    int j = threadIdx.x;
    Wt[(size_t)j * K + k] = f2bf(W[(size_t)k * 256 + j]);
}

// ---- prep: x (b,m,d) fp32 -> Xt[b][d][m] bf16 ----
__global__ void prep_x(const float* __restrict__ x, unsigned short* __restrict__ Xt){
    int b = blockIdx.x;
    int t = threadIdx.x;
    #pragma unroll
    for (int it = 0; it < 8; it++){
        int o = it * 256 + t;          // o = d*32 + m
        int d = o >> 5, m = o & 31;
        Xt[(size_t)b * 2048 + o] = f2bf(x[(size_t)b * 2048 + m * 64 + d]);
    }
}

__global__ void init_out(float* __restrict__ out, const float* __restrict__ fcb){
    int i = blockIdx.x * 256 + threadIdx.x;
    if (i < 1024) out[i] = fcb[0];
}

// ---- fused CIN stage: Y = relu(Wt^T * Z + bias); emit h-half + fc partial ----
// Z[k=(m,n), c=(bb,d)] = x[c][m] * h[c][n]; x,h persist in LDS; Z double-buffered,
// ONE barrier per kt. Block: 128 c (2 batch elems), 4 waves, j in [64w, 64w+64).
template<int NN, int LOG2NN, int KTOT, int JX, bool HAS_HOUT>
__global__ __launch_bounds__(256, 2) void cin_stage(
    const unsigned short* __restrict__ Xt,
    const unsigned short* __restrict__ Hin,
    const unsigned short* __restrict__ Wt,
    const float* __restrict__ bias,
    const float* __restrict__ fcW,      // pre-offset for this layer
    unsigned short* __restrict__ Hout,  // [b][d][n] bf16, n in [0,128); null if !HAS_HOUT
    float* __restrict__ out)
{
    constexpr int KT = KTOT / 32;
    constexpr int ZS = 40;                      // Z row stride (shorts), 80B: b128-aligned, 8-slot banks
    constexpr int XS = 40;                      // Xl row stride
    constexpr int HS = (NN == 32) ? XS : 136;   // Hl row stride (272B: b128-aligned, 8-slot banks)

    __shared__ unsigned short smem[32768];      // 64 KB
    unsigned short* const Zb0 = smem;                       // [128][40]  10240 B
    unsigned short* const Zb1 = smem + 5120;                // [128][40]  10240 B
    unsigned short* const Xl  = smem + 10240;               // [128][40]  10240 B
    unsigned short* const Hl  = (NN == 32) ? Xl : (smem + 15360);  // [128][136] 34816 B
    unsigned short* const Yl  = smem + 15360;               // epilogue overlay [n:128][c pad 136]

    const int t    = threadIdx.x;
    const int lane = t & 63;
    const int w    = t >> 6;
    const int li   = lane & 15;
    const int lq   = lane >> 4;
    const int bpair = blockIdx.x;

    // ---- one-time staging of x (and h) into LDS, fully coalesced ----
    {
        const int c  = t >> 1;
        const int b  = bpair * 2 + (c >> 6);
        const int d  = c & 63;
        const int mh = (t & 1) << 4;            // 16 shorts per thread
        const uint4* xsrc = (const uint4*)(Xt + ((size_t)b << 11) + (d << 5) + mh);
        uint4 x0 = xsrc[0], x1 = xsrc[1];
        *(uint4*)(Xl + c * XS + mh)     = x0;
        *(uint4*)(Xl + c * XS + mh + 8) = x1;
        if (NN == 128){
            const int nh = (t & 1) << 6;        // 64 shorts per thread
            const uint4* hsrc = (const uint4*)(Hin + (size_t)((b << 6) + d) * 128 + nh);
            #pragma unroll
            for (int q = 0; q < 8; q++){
                uint4 hv = hsrc[q];
                *(uint4*)(Hl + c * HS + nh + q * 8) = hv;
            }
        }
    }
    __syncthreads();

    // Z-build: thread fills Zb[zc][zkh*16 .. +16) from LDS x,h
    const int zc  = t & 127;
    const int zkh = t >> 7;
    auto build = [&](unsigned short* zbuf, int kt){
        const int kg = (kt << 5) + (zkh << 4);
        const int m  = kg >> LOG2NN;
        const int n0 = kg & (NN - 1);
        float xf = bf2f(Xl[zc * XS + m]);
        const uint4* hsrc = (const uint4*)(Hl + zc * HS + n0);
        uint4 h0 = hsrc[0], h1 = hsrc[1];
        uint4 zv[2];
        unsigned short* z = (unsigned short*)zv;
        const unsigned short* hu0 = (const unsigned short*)&h0;
        const unsigned short* hu1 = (const unsigned short*)&h1;
        #pragma unroll
        for (int q = 0; q < 8; q++) z[q]     = f2bf(xf * bf2f(hu0[q]));
        #pragma unroll
        for (int q = 0; q < 8; q++) z[q + 8] = f2bf(xf * bf2f(hu1[q]));
        uint4* zdst = (uint4*)(zbuf + zc * ZS + (zkh << 4));
        zdst[0] = zv[0];
        zdst[1] = zv[1];
    };

    // A-fragments: lane reads Wt[j = w*64 + jt*16 + li][kt*32 + lq*8 .. +8)
    const unsigned short* wbase = Wt + (size_t)((w << 6) + li) * KTOT + (lq << 3);
    auto loadA = [&](int kt, bf16x8* A){
        const unsigned short* wk = wbase + (kt << 5);
        #pragma unroll
        for (int jt = 0; jt < 4; jt++)
            A[jt] = *(const bf16x8*)(wk + (size_t)jt * 16 * KTOT);
    };

    f32x4 acc[4][8];
    #pragma unroll
    for (int jt = 0; jt < 4; jt++)
        #pragma unroll
        for (int ct = 0; ct < 8; ct++)
            acc[jt][ct] = (f32x4){0.f, 0.f, 0.f, 0.f};

    // prologue: Z(0) into buf0, A(0) into regs
    build(Zb0, 0);
    bf16x8 Acur[4];
    loadA(0, Acur);
    __syncthreads();

    for (int kt = 0; kt < KT; kt++){
        unsigned short* const Zr = (kt & 1) ? Zb1 : Zb0;   // read buf
        unsigned short* const Zw = (kt & 1) ? Zb0 : Zb1;   // write buf (for kt+1)
        bf16x8 Anx[4];
        loadA(kt + 1 < KT ? kt + 1 : kt, Anx);             // prefetch next A
        #pragma unroll
        for (int ct = 0; ct < 8; ct++){
            bf16x8 B = *(const bf16x8*)(Zr + ((ct << 4) + li) * ZS + (lq << 3));
            #pragma unroll
            for (int jt = 0; jt < 4; jt++)
                acc[jt][ct] = __builtin_amdgcn_mfma_f32_16x16x32_bf16(Acur[jt], B, acc[jt][ct], 0, 0, 0);
        }
        if (kt + 1 < KT) build(Zw, kt + 1);                // MFMA pipe hides this
        #pragma unroll
        for (int jt = 0; jt < 4; jt++) Acur[jt] = Anx[jt];
        __syncthreads();                                   // the only barrier per kt
    }

    // epilogue: bias + relu; fc partial sums; stage h-half into Yl
    float pfc0 = 0.f, pfc1 = 0.f;
    #pragma unroll
    for (int jt = 0; jt < 4; jt++){
        const int jb = (w << 6) + (jt << 4) + (lq << 2);
        float bv[4], fv[4];
        #pragma unroll
        for (int r = 0; r < 4; r++){
            int j = jb + r;
            bv[r] = bias[j];
            fv[r] = (j < JX) ? fcW[j] : 0.f;
        }
        #pragma unroll
        for (int ct = 0; ct < 8; ct++){
            f32x4 f = acc[jt][ct];
            int c = (ct << 4) + li;
            float ps = 0.f;
            #pragma unroll
            for (int r = 0; r < 4; r++){
                float y = f[r] + bv[r];
                y = y > 0.f ? y : 0.f;
                ps += fv[r] * y;
                if (HAS_HOUT){
                    int j = jb + r;
                    if (j >= 128)
                        Yl[(j - 128) * 136 + c] = f2bf(y);
                }
            }
            if (ct < 4) pfc0 += ps; else pfc1 += ps;
        }
    }
    #pragma unroll
    for (int off = 32; off; off >>= 1){
        pfc0 += __shfl_xor(pfc0, off, 64);
        pfc1 += __shfl_xor(pfc1, off, 64);
    }
    if (lane == 0){
        atomicAdd(out + bpair * 2 + 0, pfc0);
        atomicAdd(out + bpair * 2 + 1, pfc1);
    }

    if (HAS_HOUT){
        __syncthreads();
        // cooperative store: Hout[(bpair*128 + c)*128 + n] = Yl[n][c]
        const int c  = t >> 1;
        const int nh = (t & 1) << 6;
        unsigned short* gdst = Hout + (size_t)(bpair * 128 + c) * 128 + nh;
        #pragma unroll
        for (int i8 = 0; i8 < 8; i8++){
            uint4 tv;
            unsigned short* tmp = (unsigned short*)&tv;
            #pragma unroll
            for (int q = 0; q < 8; q++)
                tmp[q] = Yl[(nh + i8 * 8 + q) * 136 + c];
            *(uint4*)(gdst + i8 * 8) = tv;
        }
    }
}

extern "C" void kernel_launch(void* const* d_in, const int* in_sizes, int n_in,
                              void* d_out, int out_size, void* d_ws, size_t ws_size,
                              hipStream_t stream){
    const float* x   = (const float*)d_in[0];
    const float* W0  = (const float*)d_in[1];
    const float* b0  = (const float*)d_in[2];
    const float* W1  = (const float*)d_in[3];
    const float* b1  = (const float*)d_in[4];
    const float* W2  = (const float*)d_in[5];
    const float* b2  = (const float*)d_in[6];
    const float* fcW = (const float*)d_in[7];
    const float* fcb = (const float*)d_in[8];
    float* out = (float*)d_out;

    char* ws = (char*)d_ws;
    unsigned short* Xt  = (unsigned short*)(ws);             // 4 MB
    unsigned short* Wt0 = (unsigned short*)(ws + 4194304);   // 512 KB
    unsigned short* Wt1 = (unsigned short*)(ws + 4718592);   // 2 MB
    unsigned short* Wt2 = (unsigned short*)(ws + 6815744);   // 2 MB
    unsigned short* H0  = (unsigned short*)(ws + 8912896);   // 16 MB
    unsigned short* H1  = (unsigned short*)(ws + 25690112);  // 16 MB (end 42467328)

    prep_wt<<<1024, 256, 0, stream>>>(W0, Wt0, 1024);
    prep_wt<<<4096, 256, 0, stream>>>(W1, Wt1, 4096);
    prep_wt<<<4096, 256, 0, stream>>>(W2, Wt2, 4096);
    prep_x <<<1024, 256, 0, stream>>>(x, Xt);
    init_out<<<4, 256, 0, stream>>>(out, fcb);

    cin_stage< 32, 5, 1024, 128, true ><<<512, 256, 0, stream>>>(Xt, Xt, Wt0, b0, fcW,       H0, out);
    cin_stage<128, 7, 4096, 128, true ><<<512, 256, 0, stream>>>(Xt, H0, Wt1, b1, fcW + 128, H1, out);
    cin_stage<128, 7, 4096, 256, false><<<512, 256, 0, stream>>>(Xt, H1, Wt2, b2, fcW + 256, nullptr, out);
}